// Round 2
// baseline (106.961 us; speedup 1.0000x reference)
//
#include <hip/hip_runtime.h>

// Problem constants: O=256, I=512, K=3, C=128, B=128, T=I=512
#define O_ 256
#define I_ 512
#define K_ 3
#define C_ 128
#define B_ 128
#define T_ 512

// ---------------------------------------------------------------------------
// kA: yT[c][b] += dot(x[b, s*128:(s+1)*128], E[c, s*128:(s+1)*128])
// Split-K over s=0..3 for 4x the blocks: grid = 512 (c,s), block = 128 (b).
// Partials combined with atomicAdd (yT zeroed via hipMemsetAsync upstream).
// ---------------------------------------------------------------------------
__global__ __launch_bounds__(128) void kA(const float* __restrict__ x,
                                          const float* __restrict__ E,
                                          float* __restrict__ yT) {
    __shared__ float el[128];
    const int bx  = blockIdx.x;
    const int c   = bx >> 2;
    const int s   = bx & 3;
    const int tid = threadIdx.x;                    // = b
    el[tid] = E[(size_t)c * I_ + s * 128 + tid];    // coalesced 512 B
    __syncthreads();

    const float4* x4 = (const float4*)(x + (size_t)tid * I_ + s * 128);
    const float4* e4 = (const float4*)el;
    float acc = 0.0f;
#pragma unroll 8
    for (int i = 0; i < 32; ++i) {
        float4 xv = x4[i];
        float4 ev = e4[i];                          // LDS broadcast
        acc += xv.x * ev.x + xv.y * ev.y + xv.z * ev.z + xv.w * ev.w;
    }
    atomicAdd(&yT[c * B_ + tid], acc);              // 4-way contention only
}

// ---------------------------------------------------------------------------
// kBC (fused): per block (o, b-half):
//   phase 1: Z[jj][bl] = sum_c CV[o,jj,c] * yT[c][b]  -> LDS (zl[bl][jj] f4)
//   phase 2: out[o, b, t] = lerp weights  .  Z[:, b]  -> 128 KB stream/block
// grid = O_*2 = 512 blocks, block = 256.
// ---------------------------------------------------------------------------
__global__ __launch_bounds__(256) void kBC(const float* __restrict__ CV,
                                           const float* __restrict__ yT,
                                           float* __restrict__ out) {
    __shared__ float cvl[4 * C_];                   // 2 KB: CV[o] slice
    __shared__ float zl[64 * 4];                    // 1 KB: zl[bl][jj]
    const int bx  = blockIdx.x;
    const int o   = bx >> 1;
    const int bh  = bx & 1;
    const int tid = threadIdx.x;

    if (tid < 128)                                  // 512 contiguous floats
        ((float4*)cvl)[tid] = ((const float4*)(CV + (size_t)o * 512))[tid];
    __syncthreads();

    // ---- phase 1: 256 threads = (jj in 0..3) x (bl in 0..63) ----
    {
        const int bl = tid & 63;
        const int jj = tid >> 6;
        const float* yrow = yT + bh * 64 + bl;      // stride C over c
        const float* cvr  = cvl + jj * C_;
        float acc = 0.0f;
#pragma unroll 8
        for (int c = 0; c < C_; ++c)
            acc += cvr[c] * yrow[c * B_];           // yT coalesced, cv broadcast
        zl[bl * 4 + jj] = acc;
    }
    __syncthreads();

    // ---- phase 2: (pos = float4 column 0..127) x (rh = row parity) ----
    const int pos = tid & 127;
    const int rh  = tid >> 7;

    float4 w[4];                                    // lerp weights, once
#pragma unroll
    for (int u = 0; u < 4; ++u) {
        const int   t  = pos * 4 + u;
        const float ts = (float)t * (3.0f / 511.0f);
        int j = (int)ts;
        if (j > K_ - 1) j = K_ - 1;
        const float tl = ts - (float)j;
        const float om = 1.0f - tl;
        float4 wu;
        wu.x = (j == 0) ? om : 0.0f;
        wu.y = (j == 0) ? tl : ((j == 1) ? om : 0.0f);
        wu.z = (j == 1) ? tl : ((j == 2) ? om : 0.0f);
        wu.w = (j == 2) ? tl : 0.0f;
        w[u] = wu;
    }

    const float4* zl4  = (const float4*)zl;
    float4*       out4 = (float4*)out;
    const size_t rowbase = (size_t)o * B_ + bh * 64;

#pragma unroll 8
    for (int bl = rh; bl < 64; bl += 2) {           // 32 rows per thread-half
        const float4 z = zl4[bl];                   // LDS broadcast
        float4 o4;
        o4.x = w[0].x * z.x + w[0].y * z.y + w[0].z * z.z + w[0].w * z.w;
        o4.y = w[1].x * z.x + w[1].y * z.y + w[1].z * z.z + w[1].w * z.w;
        o4.z = w[2].x * z.x + w[2].y * z.y + w[2].z * z.z + w[2].w * z.w;
        o4.w = w[3].x * z.x + w[3].y * z.y + w[3].z * z.z + w[3].w * z.w;
        out4[(rowbase + bl) * (T_ / 4) + pos] = o4; // coalesced 1 KB/wave
    }
}

// ---------------------------------------------------------------------------
// Inputs: x (B,I) f32 | control_points (O,K+1) unused | control_values
// (O,K+1,C) f32 | expansion_matrix (C,I) f32.  Output (O,B,T) f32.
// Workspace: yT = C_*B_ floats (64 KB), zeroed each call.
// ---------------------------------------------------------------------------
extern "C" void kernel_launch(void* const* d_in, const int* in_sizes, int n_in,
                              void* d_out, int out_size, void* d_ws, size_t ws_size,
                              hipStream_t stream) {
    const float* x  = (const float*)d_in[0];
    const float* CV = (const float*)d_in[2];
    const float* E  = (const float*)d_in[3];
    float* out = (float*)d_out;
    float* yT  = (float*)d_ws;                      // 64 KB

    hipMemsetAsync(yT, 0, C_ * B_ * sizeof(float), stream);
    kA <<<C_ * 4, 128, 0, stream>>>(x, E, yT);
    kBC<<<O_ * 2, 256, 0, stream>>>(CV, yT, out);
}

// Round 3
// 105.759 us; speedup vs baseline: 1.0114x; 1.0114x over previous
//
#include <hip/hip_runtime.h>

// Problem constants: O=256, I=512, K=3, C=128, B=128, T=I=512
#define O_ 256
#define I_ 512
#define K_ 3
#define C_ 128
#define B_ 128
#define T_ 512

// ---------------------------------------------------------------------------
// kA: yT[c][b] = dot(x[b,:], E[c,:])   (y = x @ E^T, stored transposed [c][b])
// grid = 512 blocks = (c in 0..127) x (q in 0..3); block = 128 threads.
// Thread (b_local = tid>>2, s = tid&3) computes a length-128 partial dot over
// segment s; partials combined with __shfl_xor across the 4 lanes of each b.
// No atomics, no zero-init needed.
// ---------------------------------------------------------------------------
__global__ __launch_bounds__(128) void kA(const float* __restrict__ x,
                                          const float* __restrict__ E,
                                          float* __restrict__ yT) {
    __shared__ float4 el4[I_ / 4];                  // full E row: 2 KB
    const int bx = blockIdx.x;
    const int c  = bx >> 2;
    const int q  = bx & 3;
    const int tid = threadIdx.x;

    el4[tid] = ((const float4*)(E + (size_t)c * I_))[tid];   // coalesced 2 KB
    __syncthreads();

    const int bl = tid >> 2;                        // 0..31
    const int s  = tid & 3;                         // segment 0..3
    const int b  = q * 32 + bl;

    const float4* x4 = (const float4*)(x + (size_t)b * I_ + s * 128);
    const float4* e4 = el4 + s * 32;
    float acc = 0.0f;
#pragma unroll 8
    for (int i = 0; i < 32; ++i) {
        float4 xv = x4[i];
        float4 ev = e4[i];
        acc += xv.x * ev.x + xv.y * ev.y + xv.z * ev.z + xv.w * ev.w;
    }
    acc += __shfl_xor(acc, 1);                      // fold s pairs
    acc += __shfl_xor(acc, 2);
    if (s == 0) yT[c * B_ + b] = acc;               // 16 lanes/wave, 64 B
}

// ---------------------------------------------------------------------------
// kBC (fused): per block (o, b-half):
//   phase 1: zl[bl][jj] = sum_c CV[o,jj,c] * yT[c][b]      (into LDS)
//   phase 2: out[o,b,t] = lerp-weights(t) . zl[bl][:]      (64 MB stream)
// grid = O_*2 = 512 blocks, block = 256.
// ---------------------------------------------------------------------------
__global__ __launch_bounds__(256) void kBC(const float* __restrict__ CV,
                                           const float* __restrict__ yT,
                                           float* __restrict__ out) {
    __shared__ float cvl[4 * C_];                   // 2 KB: CV[o] slice
    __shared__ float zl[64 * 4];                    // 1 KB: zl[bl][jj]
    const int bx  = blockIdx.x;
    const int o   = bx >> 1;
    const int bh  = bx & 1;
    const int tid = threadIdx.x;

    if (tid < 128)                                  // 512 contiguous floats
        ((float4*)cvl)[tid] = ((const float4*)(CV + (size_t)o * 512))[tid];
    __syncthreads();

    // ---- phase 1: 256 threads = (jj in 0..3) x (bl in 0..63) ----
    {
        const int bl = tid & 63;
        const int jj = tid >> 6;
        const float* yrow = yT + bh * 64 + bl;      // stride B_ over c
        const float* cvr  = cvl + jj * C_;
        float acc = 0.0f;
#pragma unroll 8
        for (int c = 0; c < C_; ++c)
            acc += cvr[c] * yrow[c * B_];           // yT coalesced, cv broadcast
        zl[bl * 4 + jj] = acc;
    }
    __syncthreads();

    // ---- phase 2: (pos = float4 column 0..127) x (rh = row parity) ----
    const int pos = tid & 127;
    const int rh  = tid >> 7;

    float4 w[4];                                    // lerp weights, once
#pragma unroll
    for (int u = 0; u < 4; ++u) {
        const int   t  = pos * 4 + u;
        const float ts = (float)t * (3.0f / 511.0f);
        int j = (int)ts;
        if (j > K_ - 1) j = K_ - 1;
        const float tl = ts - (float)j;
        const float om = 1.0f - tl;
        float4 wu;
        wu.x = (j == 0) ? om : 0.0f;
        wu.y = (j == 0) ? tl : ((j == 1) ? om : 0.0f);
        wu.z = (j == 1) ? tl : ((j == 2) ? om : 0.0f);
        wu.w = (j == 2) ? tl : 0.0f;
        w[u] = wu;
    }

    const float4* zl4  = (const float4*)zl;
    float4*       out4 = (float4*)out;
    const size_t rowbase = (size_t)o * B_ + bh * 64;

#pragma unroll 8
    for (int bl = rh; bl < 64; bl += 2) {           // 32 rows per thread-half
        const float4 z = zl4[bl];                   // LDS broadcast
        float4 o4;
        o4.x = w[0].x * z.x + w[0].y * z.y + w[0].z * z.z + w[0].w * z.w;
        o4.y = w[1].x * z.x + w[1].y * z.y + w[1].z * z.z + w[1].w * z.w;
        o4.z = w[2].x * z.x + w[2].y * z.y + w[2].z * z.z + w[2].w * z.w;
        o4.w = w[3].x * z.x + w[3].y * z.y + w[3].z * z.z + w[3].w * z.w;
        out4[(rowbase + bl) * (T_ / 4) + pos] = o4; // 1 KB/wave, coalesced
    }
}

// ---------------------------------------------------------------------------
// Inputs: x (B,I) f32 | control_points (O,K+1) unused | control_values
// (O,K+1,C) f32 | expansion_matrix (C,I) f32.  Output (O,B,T) f32.
// Workspace: yT = C_*B_ floats (64 KB). Exactly 2 dispatches, no memset.
// ---------------------------------------------------------------------------
extern "C" void kernel_launch(void* const* d_in, const int* in_sizes, int n_in,
                              void* d_out, int out_size, void* d_ws, size_t ws_size,
                              hipStream_t stream) {
    const float* x  = (const float*)d_in[0];
    const float* CV = (const float*)d_in[2];
    const float* E  = (const float*)d_in[3];
    float* out = (float*)d_out;
    float* yT  = (float*)d_ws;                      // 64 KB

    kA <<<C_ * 4, 128, 0, stream>>>(x, E, yT);
    kBC<<<O_ * 2, 256, 0, stream>>>(CV, yT, out);
}

// Round 4
// 92.370 us; speedup vs baseline: 1.1580x; 1.1450x over previous
//
#include <hip/hip_runtime.h>

// Problem constants: O=256, I=512, K=3, C=128, B=128, T=I=512
#define O_ 256
#define I_ 512
#define K_ 3
#define C_ 128
#define B_ 128
#define T_ 512

// ---------------------------------------------------------------------------
// kA: yT[c][b] = dot(x[b,:], E[c,:])   (y = x @ E^T, stored transposed [c][b])
// grid = 512 blocks = (c 0..127) x (q 0..3); block = 128.
// Thread (b_local = tid>>2, s = tid&3) does a length-128 segment dot;
// __shfl_xor folds the 4 segments. No atomics, no zero-init.
// ---------------------------------------------------------------------------
__global__ __launch_bounds__(128) void kA(const float* __restrict__ x,
                                          const float* __restrict__ E,
                                          float* __restrict__ yT) {
    __shared__ float4 el4[I_ / 4];                  // full E row: 2 KB
    const int bx = blockIdx.x;
    const int c  = bx >> 2;
    const int q  = bx & 3;
    const int tid = threadIdx.x;

    el4[tid] = ((const float4*)(E + (size_t)c * I_))[tid];   // coalesced 2 KB
    __syncthreads();

    const int bl = tid >> 2;                        // 0..31
    const int s  = tid & 3;                         // segment 0..3
    const int b  = q * 32 + bl;

    const float4* x4 = (const float4*)(x + (size_t)b * I_ + s * 128);
    const float4* e4 = el4 + s * 32;
    float acc = 0.0f;
#pragma unroll 8
    for (int i = 0; i < 32; ++i) {
        float4 xv = x4[i];
        float4 ev = e4[i];
        acc += xv.x * ev.x + xv.y * ev.y + xv.z * ev.z + xv.w * ev.w;
    }
    acc += __shfl_xor(acc, 1);
    acc += __shfl_xor(acc, 2);
    if (s == 0) yT[c * B_ + b] = acc;
}

// ---------------------------------------------------------------------------
// kBC: per block (o, bq = 16-row batch of b):
//   phase 1 (64 threads): zl[bl][jj] = sum_c CV[o,jj,c] * yT[c][bq*16+bl]
//   phase 2 (256 threads): stream 16 rows x 512 t = 32 KB coalesced stores
// grid = O_*8 = 2048 blocks (8 blocks/CU, 32 waves/CU for the store stream).
// ---------------------------------------------------------------------------
__global__ __launch_bounds__(256) void kBC(const float* __restrict__ CV,
                                           const float* __restrict__ yT,
                                           float* __restrict__ out) {
    __shared__ float cvl[4 * C_];                   // 2 KB: CV[o] slice
    __shared__ float zl[16 * 4];                    // 256 B: zl[bl][jj]
    const int bx  = blockIdx.x;
    const int o   = bx >> 3;
    const int bq  = bx & 7;                         // 16-row batch
    const int tid = threadIdx.x;

    if (tid < 128)                                  // 512 contiguous floats
        ((float4*)cvl)[tid] = ((const float4*)(CV + (size_t)o * 512))[tid];
    __syncthreads();

    // ---- phase 1: threads 0..63 = (bl 0..15) x (jj 0..3) ----
    if (tid < 64) {
        const int bl = tid >> 2;
        const int jj = tid & 3;
        const float* yrow = yT + bq * 16 + bl;      // stride B_ over c
        const float* cvr  = cvl + jj * C_;
        float acc = 0.0f;
#pragma unroll 8
        for (int c = 0; c < C_; ++c)
            acc += cvr[c] * yrow[c * B_];           // yT in L1/L2, cv broadcast
        zl[bl * 4 + jj] = acc;
    }
    __syncthreads();

    // ---- phase 2: (pos = float4 column 0..127) x (rh = row parity) ----
    const int pos = tid & 127;
    const int rh  = tid >> 7;

    float4 w[4];                                    // lerp weights, once
#pragma unroll
    for (int u = 0; u < 4; ++u) {
        const int   t  = pos * 4 + u;
        const float ts = (float)t * (3.0f / 511.0f);
        int j = (int)ts;
        if (j > K_ - 1) j = K_ - 1;
        const float tl = ts - (float)j;
        const float om = 1.0f - tl;
        float4 wu;
        wu.x = (j == 0) ? om : 0.0f;
        wu.y = (j == 0) ? tl : ((j == 1) ? om : 0.0f);
        wu.z = (j == 1) ? tl : ((j == 2) ? om : 0.0f);
        wu.w = (j == 2) ? tl : 0.0f;
        w[u] = wu;
    }

    const float4* zl4  = (const float4*)zl;
    float4*       out4 = (float4*)out;
    const size_t rowbase = (size_t)o * B_ + bq * 16;

#pragma unroll
    for (int it = 0; it < 8; ++it) {
        const int bl = rh + it * 2;                 // 0..15
        const float4 z = zl4[bl];                   // LDS broadcast
        float4 o4;
        o4.x = w[0].x * z.x + w[0].y * z.y + w[0].z * z.z + w[0].w * z.w;
        o4.y = w[1].x * z.x + w[1].y * z.y + w[1].z * z.z + w[1].w * z.w;
        o4.z = w[2].x * z.x + w[2].y * z.y + w[2].z * z.z + w[2].w * z.w;
        o4.w = w[3].x * z.x + w[3].y * z.y + w[3].z * z.z + w[3].w * z.w;
        out4[(rowbase + bl) * (T_ / 4) + pos] = o4; // 1 KB/wave, coalesced
    }
}

// ---------------------------------------------------------------------------
// Inputs: x (B,I) f32 | control_points (O,K+1) unused | control_values
// (O,K+1,C) f32 | expansion_matrix (C,I) f32.  Output (O,B,T) f32.
// Workspace: yT = C_*B_ floats (64 KB). Exactly 2 dispatches.
// ---------------------------------------------------------------------------
extern "C" void kernel_launch(void* const* d_in, const int* in_sizes, int n_in,
                              void* d_out, int out_size, void* d_ws, size_t ws_size,
                              hipStream_t stream) {
    const float* x  = (const float*)d_in[0];
    const float* CV = (const float*)d_in[2];
    const float* E  = (const float*)d_in[3];
    float* out = (float*)d_out;
    float* yT  = (float*)d_ws;                      // 64 KB

    kA <<<C_ * 4, 128, 0, stream>>>(x, E, yT);
    kBC<<<O_ * 8, 256, 0, stream>>>(CV, yT, out);
}

// Round 5
// 89.645 us; speedup vs baseline: 1.1932x; 1.0304x over previous
//
#include <hip/hip_runtime.h>

// Problem constants: O=256, I=512, K=3, C=128, B=128, T=I=512
#define O_ 256
#define I_ 512
#define K_ 3
#define C_ 128
#define B_ 128
#define T_ 512

// ---------------------------------------------------------------------------
// kA: yT[c][b] = dot(x[b,:], E[c,:])   (y = x @ E^T, stored transposed [c][b])
// grid = 512 blocks = (c 0..127) x (q 0..3); block = 128.
// Thread (b_local = tid>>2, s = tid&3) does a length-128 segment dot;
// __shfl_xor folds the 4 segments. No atomics, no zero-init.
// ---------------------------------------------------------------------------
__global__ __launch_bounds__(128) void kA(const float* __restrict__ x,
                                          const float* __restrict__ E,
                                          float* __restrict__ yT) {
    __shared__ float4 el4[I_ / 4];                  // full E row: 2 KB
    const int bx = blockIdx.x;
    const int c  = bx >> 2;
    const int q  = bx & 3;
    const int tid = threadIdx.x;

    el4[tid] = ((const float4*)(E + (size_t)c * I_))[tid];   // coalesced 2 KB
    __syncthreads();

    const int bl = tid >> 2;                        // 0..31
    const int s  = tid & 3;                         // segment 0..3
    const int b  = q * 32 + bl;

    const float4* x4 = (const float4*)(x + (size_t)b * I_ + s * 128);
    const float4* e4 = el4 + s * 32;
    float acc = 0.0f;
#pragma unroll 8
    for (int i = 0; i < 32; ++i) {
        float4 xv = x4[i];
        float4 ev = e4[i];
        acc += xv.x * ev.x + xv.y * ev.y + xv.z * ev.z + xv.w * ev.w;
    }
    acc += __shfl_xor(acc, 1);
    acc += __shfl_xor(acc, 2);
    if (s == 0) yT[c * B_ + b] = acc;
}

// ---------------------------------------------------------------------------
// kBC: per block (o, bq = 16-row batch of b):
//   phase 1 (ALL 256 threads): thread (s, bl, jj) sums c in [s*32,(s+1)*32):
//     zp[bl][jj][s] = sum_c CV[o,jj,c] * yT[c][bq*16+bl]; fold s via LDS.
//   phase 2 (256 threads): stream 16 rows x 512 t = 32 KB coalesced stores.
// grid = O_*8 = 2048 blocks (8 blocks/CU, 32 waves/CU for the store stream).
// ---------------------------------------------------------------------------
__global__ __launch_bounds__(256) void kBC(const float* __restrict__ CV,
                                           const float* __restrict__ yT,
                                           float* __restrict__ out) {
    __shared__ float cvl[4 * C_];                   // 2 KB: CV[o] slice
    __shared__ float zp[16 * 4 * 4];                // 1 KB: zp[bl][jj][s]
    __shared__ float zl[16 * 4];                    // 256 B: zl[bl][jj]
    const int bx  = blockIdx.x;
    const int o   = bx >> 3;
    const int bq  = bx & 7;                         // 16-row batch of b
    const int tid = threadIdx.x;

    if (tid < 128)                                  // 512 contiguous floats
        ((float4*)cvl)[tid] = ((const float4*)(CV + (size_t)o * 512))[tid];

    // ---- phase 2 weights first: pure VALU, overlaps phase-1 load latency --
    const int pos = tid & 127;
    const int rh  = tid >> 7;
    float4 w[4];
#pragma unroll
    for (int u = 0; u < 4; ++u) {
        const int   t  = pos * 4 + u;
        const float ts = (float)t * (3.0f / 511.0f);
        int j = (int)ts;
        if (j > K_ - 1) j = K_ - 1;
        const float tl = ts - (float)j;
        const float om = 1.0f - tl;
        float4 wu;
        wu.x = (j == 0) ? om : 0.0f;
        wu.y = (j == 0) ? tl : ((j == 1) ? om : 0.0f);
        wu.z = (j == 1) ? tl : ((j == 2) ? om : 0.0f);
        wu.w = (j == 2) ? tl : 0.0f;
        w[u] = wu;
    }
    __syncthreads();                                // cvl ready

    // ---- phase 1: 256 threads = (s 0..3 = wave) x (bl 0..15) x (jj 0..3) --
    {
        const int s  = tid >> 6;                    // c-segment (= wave id)
        const int bl = (tid & 63) >> 2;
        const int jj = tid & 3;
        const float* yrow = yT + bq * 16 + bl;      // stride B_ over c
        const float* cvr  = cvl + jj * C_ + s * 32;
        float acc = 0.0f;
#pragma unroll 8
        for (int c = 0; c < 32; ++c)
            acc += cvr[c] * yrow[(s * 32 + c) * B_];
        zp[(bl * 4 + jj) * 4 + s] = acc;
    }
    __syncthreads();
    if (tid < 64) {                                 // fold the 4 partials
        const float* p = zp + tid * 4;
        zl[tid] = (p[0] + p[1]) + (p[2] + p[3]);
    }
    __syncthreads();

    // ---- phase 2: (pos = float4 column 0..127) x (rh = row parity) ----
    const float4* zl4  = (const float4*)zl;
    float4*       out4 = (float4*)out;
    const size_t rowbase = (size_t)o * B_ + bq * 16;

#pragma unroll
    for (int it = 0; it < 8; ++it) {
        const int bl = rh + it * 2;                 // 0..15
        const float4 z = zl4[bl];                   // LDS broadcast
        float4 o4;
        o4.x = w[0].x * z.x + w[0].y * z.y + w[0].z * z.z + w[0].w * z.w;
        o4.y = w[1].x * z.x + w[1].y * z.y + w[1].z * z.z + w[1].w * z.w;
        o4.z = w[2].x * z.x + w[2].y * z.y + w[2].z * z.z + w[2].w * z.w;
        o4.w = w[3].x * z.x + w[3].y * z.y + w[3].z * z.z + w[3].w * z.w;
        out4[(rowbase + bl) * (T_ / 4) + pos] = o4; // 1 KB/wave, coalesced
    }
}

// ---------------------------------------------------------------------------
// Inputs: x (B,I) f32 | control_points (O,K+1) unused | control_values
// (O,K+1,C) f32 | expansion_matrix (C,I) f32.  Output (O,B,T) f32.
// Workspace: yT = C_*B_ floats (64 KB). Exactly 2 dispatches.
// ---------------------------------------------------------------------------
extern "C" void kernel_launch(void* const* d_in, const int* in_sizes, int n_in,
                              void* d_out, int out_size, void* d_ws, size_t ws_size,
                              hipStream_t stream) {
    const float* x  = (const float*)d_in[0];
    const float* CV = (const float*)d_in[2];
    const float* E  = (const float*)d_in[3];
    float* out = (float*)d_out;
    float* yT  = (float*)d_ws;                      // 64 KB

    kA <<<C_ * 4, 128, 0, stream>>>(x, E, yT);
    kBC<<<O_ * 8, 256, 0, stream>>>(CV, yT, out);
}

// Round 7
// 89.235 us; speedup vs baseline: 1.1986x; 1.0046x over previous
//
#include <hip/hip_runtime.h>

// Problem constants: O=256, I=512, K=3, C=128, B=128, T=I=512
#define O_ 256
#define I_ 512
#define K_ 3
#define C_ 128
#define B_ 128
#define T_ 512

// Native clang vector for __builtin_nontemporal_store (HIP float4 is a class
// type the builtin rejects; this alias is layout-identical).
typedef float nfloat4 __attribute__((ext_vector_type(4)));

// ---------------------------------------------------------------------------
// kA: yT[c][b] = dot(x[b,:], E[c,:])   (y = x @ E^T, stored transposed [c][b])
// grid = 512 blocks = (c 0..127) x (q 0..3); block = 128.
// Thread (b_local = tid>>2, s = tid&3) does a length-128 segment dot;
// __shfl_xor folds the 4 segments. No atomics, no zero-init.
// ---------------------------------------------------------------------------
__global__ __launch_bounds__(128) void kA(const float* __restrict__ x,
                                          const float* __restrict__ E,
                                          float* __restrict__ yT) {
    __shared__ float4 el4[I_ / 4];                  // full E row: 2 KB
    const int bx = blockIdx.x;
    const int c  = bx >> 2;
    const int q  = bx & 3;
    const int tid = threadIdx.x;

    el4[tid] = ((const float4*)(E + (size_t)c * I_))[tid];   // coalesced 2 KB
    __syncthreads();

    const int bl = tid >> 2;                        // 0..31
    const int s  = tid & 3;                         // segment 0..3
    const int b  = q * 32 + bl;

    const float4* x4 = (const float4*)(x + (size_t)b * I_ + s * 128);
    const float4* e4 = el4 + s * 32;
    float acc = 0.0f;
#pragma unroll
    for (int i = 0; i < 32; ++i) {
        float4 xv = x4[i];
        float4 ev = e4[i];
        acc += xv.x * ev.x + xv.y * ev.y + xv.z * ev.z + xv.w * ev.w;
    }
    acc += __shfl_xor(acc, 1);
    acc += __shfl_xor(acc, 2);
    if (s == 0) yT[c * B_ + b] = acc;
}

// ---------------------------------------------------------------------------
// kBC: per block (o, bq = 16-row batch of b):
//   phase 1 (ALL 256 threads): thread (s, bl, jj) sums c in [s*32,(s+1)*32):
//     zp[bl][jj][s] = sum_c CV[o,jj,c] * yT[c][bq*16+bl]; fold s via LDS.
//   phase 2 (256 threads): stream 16 rows x 512 t = 32 KB via NT stores
//     (output is never re-read: keep it out of L2 so yT/CV stay hot).
// grid = O_*8 = 2048 blocks (8 blocks/CU, 32 waves/CU for the store stream).
// ---------------------------------------------------------------------------
__global__ __launch_bounds__(256) void kBC(const float* __restrict__ CV,
                                           const float* __restrict__ yT,
                                           float* __restrict__ out) {
    __shared__ float cvl[4 * C_];                   // 2 KB: CV[o] slice
    __shared__ float zp[16 * 4 * 4];                // 1 KB: zp[bl][jj][s]
    __shared__ float zl[16 * 4];                    // 256 B: zl[bl][jj]
    const int bx  = blockIdx.x;
    const int o   = bx >> 3;
    const int bq  = bx & 7;                         // 16-row batch of b
    const int tid = threadIdx.x;

    if (tid < 128)                                  // 512 contiguous floats
        ((float4*)cvl)[tid] = ((const float4*)(CV + (size_t)o * 512))[tid];

    // ---- phase 2 weights first: pure VALU, overlaps phase-1 load latency --
    const int pos = tid & 127;
    const int rh  = tid >> 7;
    float4 w[4];
#pragma unroll
    for (int u = 0; u < 4; ++u) {
        const int   t  = pos * 4 + u;
        const float ts = (float)t * (3.0f / 511.0f);
        int j = (int)ts;
        if (j > K_ - 1) j = K_ - 1;
        const float tl = ts - (float)j;
        const float om = 1.0f - tl;
        float4 wu;
        wu.x = (j == 0) ? om : 0.0f;
        wu.y = (j == 0) ? tl : ((j == 1) ? om : 0.0f);
        wu.z = (j == 1) ? tl : ((j == 2) ? om : 0.0f);
        wu.w = (j == 2) ? tl : 0.0f;
        w[u] = wu;
    }
    __syncthreads();                                // cvl ready

    // ---- phase 1: 256 threads = (s 0..3 = wave) x (bl 0..15) x (jj 0..3) --
    {
        const int s  = tid >> 6;                    // c-segment (= wave id)
        const int bl = (tid & 63) >> 2;
        const int jj = tid & 3;
        const float* yrow = yT + bq * 16 + bl;      // stride B_ over c
        const float* cvr  = cvl + jj * C_ + s * 32;
        float acc = 0.0f;
#pragma unroll
        for (int c = 0; c < 32; ++c)                // full unroll: max MLP
            acc += cvr[c] * yrow[(s * 32 + c) * B_];
        zp[(bl * 4 + jj) * 4 + s] = acc;
    }
    __syncthreads();
    if (tid < 64) {                                 // fold the 4 partials
        const float* p = zp + tid * 4;
        zl[tid] = (p[0] + p[1]) + (p[2] + p[3]);
    }
    __syncthreads();

    // ---- phase 2: (pos = float4 column 0..127) x (rh = row parity) ----
    const float4* zl4  = (const float4*)zl;
    nfloat4*      out4 = (nfloat4*)out;
    const size_t rowbase = (size_t)o * B_ + bq * 16;

#pragma unroll
    for (int it = 0; it < 8; ++it) {
        const int bl = rh + it * 2;                 // 0..15
        const float4 z = zl4[bl];                   // LDS broadcast
        nfloat4 o4;
        o4.x = w[0].x * z.x + w[0].y * z.y + w[0].z * z.z + w[0].w * z.w;
        o4.y = w[1].x * z.x + w[1].y * z.y + w[1].z * z.z + w[1].w * z.w;
        o4.z = w[2].x * z.x + w[2].y * z.y + w[2].z * z.z + w[2].w * z.w;
        o4.w = w[3].x * z.x + w[3].y * z.y + w[3].z * z.z + w[3].w * z.w;
        // Non-temporal: output is write-once, never re-read by the GPU.
        __builtin_nontemporal_store(o4, &out4[(rowbase + bl) * (T_ / 4) + pos]);
    }
}

// ---------------------------------------------------------------------------
// Inputs: x (B,I) f32 | control_points (O,K+1) unused | control_values
// (O,K+1,C) f32 | expansion_matrix (C,I) f32.  Output (O,B,T) f32.
// Workspace: yT = C_*B_ floats (64 KB). Exactly 2 dispatches.
// ---------------------------------------------------------------------------
extern "C" void kernel_launch(void* const* d_in, const int* in_sizes, int n_in,
                              void* d_out, int out_size, void* d_ws, size_t ws_size,
                              hipStream_t stream) {
    const float* x  = (const float*)d_in[0];
    const float* CV = (const float*)d_in[2];
    const float* E  = (const float*)d_in[3];
    float* out = (float*)d_out;
    float* yT  = (float*)d_ws;                      // 64 KB

    kA <<<C_ * 4, 128, 0, stream>>>(x, E, yT);
    kBC<<<O_ * 8, 256, 0, stream>>>(CV, yT, out);
}